// Round 10
// baseline (981.578 us; speedup 1.0000x reference)
//
#include <hip/hip_runtime.h>

#define NN 20000
#define EE 320000
#define BB 64
#define DD 256
#define DEPTH 3
#define NT (NN + BB)   // h rows + hs rows appended (NT = 20064 = 32*627)

typedef __attribute__((ext_vector_type(8))) short short8;
typedef __attribute__((ext_vector_type(4))) float floatx4;

// ---------------------------------------------------------------- bf16 split helpers
__device__ __forceinline__ short f2bf(float x) {
  union { float f; unsigned u; } v; v.f = x;
  unsigned r = v.u + 0x7fffu + ((v.u >> 16) & 1u);  // RNE
  return (short)(r >> 16);
}
__device__ __forceinline__ float bf2f(short s) {
  union { unsigned u; float f; } v; v.u = ((unsigned)(unsigned short)s) << 16;
  return v.f;
}

// ---------------------------------------------------------------- reductions
__device__ __forceinline__ float blockSum256(float v, float* tmp) {
  #pragma unroll
  for (int o = 32; o > 0; o >>= 1) v += __shfl_down(v, o, 64);
  if ((threadIdx.x & 63) == 0) tmp[threadIdx.x >> 6] = v;
  __syncthreads();
  float r = tmp[0] + tmp[1] + tmp[2] + tmp[3];
  __syncthreads();
  return r;
}

// ---------------------------------------------------------------- M2/M3 -> split transposed B
__global__ __launch_bounds__(256) void kM(const float* __restrict__ W2,
                                          const float* __restrict__ W3,
                                          const float* __restrict__ linW,
                                          short* __restrict__ Bth,
                                          short* __restrict__ Btl) {
  int i = blockIdx.x & 255;
  bool second = blockIdx.x >= 256;
  const float* W = second ? W3 : W2;
  const float* L = linW + (second ? DD * DD : 0);
  int j = threadIdx.x;
  float acc = 0.f;
  #pragma unroll 4
  for (int k = 0; k < DD; k++) acc = fmaf(W[i * DD + k], L[k * DD + j], acc);
  short hi = f2bf(acc);
  short lo = f2bf(acc - bf2f(hi));
  int kk = second ? (DD + i) : i;
  Bth[(size_t)j * 512 + kk] = hi;
  Btl[(size_t)j * 512 + kk] = lo;
}

// ---------------------------------------------------------------- count (first) + encode (wave-per-row)
// cntb (64 bins) via LDS histogram: direct atomics on 64 ints = one hot L2 line,
// 20K serialized RMWs ~ 25us (round-9 kEncCount counter evidence: 47us @ VALU 5.8%).
#define NCB ((EE + 255) / 256)   // 1250 count blocks, scheduled first
__global__ __launch_bounds__(256) void kEncCount(const float* __restrict__ X,
                                                 const float* __restrict__ Xs,
                                                 const float* __restrict__ W1,
                                                 float* __restrict__ h,
                                                 const int* __restrict__ dst,
                                                 const int* __restrict__ bassign,
                                                 int* cntn, int* cntb) {
  __shared__ int hb[64];
  int bid = blockIdx.x, j = threadIdx.x;
  if (bid < NCB) {
    if (j < 64) hb[j] = 0;
    __syncthreads();
    int t = bid * 256 + j;
    if (t < EE) atomicAdd(&cntn[dst[t]], 1);
    if (t < NN) atomicAdd(&hb[bassign[t]], 1);   // LDS atomic
    __syncthreads();
    if (j < 64 && hb[j] > 0) atomicAdd(&cntb[j], hb[j]);
  } else {
    int r = (bid - NCB) * 4 + (j >> 6);     // wave-per-row
    int lane = j & 63, c0 = lane * 4;
    const float* x = (r < NN) ? (X + (size_t)r * 2) : (Xs + (size_t)(r - NN) * 2);
    float x0 = x[0], x1 = x[1];
    float4 wa = *(const float4*)(W1 + c0);
    float4 wb = *(const float4*)(W1 + DD + c0);
    float4 v;
    v.x = fmaxf(fmaf(x0, wa.x, x1 * wb.x), 0.f);
    v.y = fmaxf(fmaf(x0, wa.y, x1 * wb.y), 0.f);
    v.z = fmaxf(fmaf(x0, wa.z, x1 * wb.z), 0.f);
    v.w = fmaxf(fmaf(x0, wa.w, x1 * wb.w), 0.f);
    float ss = v.x * v.x + v.y * v.y + v.z * v.z + v.w * v.w;
    #pragma unroll
    for (int o = 1; o < 64; o <<= 1) ss += __shfl_xor(ss, o, 64);
    float inv = 1.f / fmaxf(sqrtf(ss), 1e-12f);
    v.x *= inv; v.y *= inv; v.z *= inv; v.w *= inv;
    *(float4*)(h + (size_t)r * DD + c0) = v;
  }
}

// ---------------------------------------------------------------- CSR scan
__global__ __launch_bounds__(1024) void kScan(const int* __restrict__ cntn,
                                              int* offn, int* curn,
                                              const int* __restrict__ cntb,
                                              int* offb, int* curb) {
  __shared__ int sums[1024];
  int t = threadIdx.x;
  const int CH = 20;  // 1024*20 = 20480 >= NN
  int base = t * CH;
  int local[CH];
  int s = 0;
  #pragma unroll
  for (int i = 0; i < CH; i++) {
    int idx = base + i;
    int v = (idx < NN) ? cntn[idx] : 0;
    local[i] = s;
    s += v;
  }
  sums[t] = s;
  __syncthreads();
  for (int o = 1; o < 1024; o <<= 1) {
    int x = (t >= o) ? sums[t - o] : 0;
    __syncthreads();
    sums[t] += x;
    __syncthreads();
  }
  int excl = sums[t] - s;
  #pragma unroll
  for (int i = 0; i < CH; i++) {
    int idx = base + i;
    if (idx < NN) {
      int o = excl + local[i];
      offn[idx] = o;
      curn[idx] = o;
    }
  }
  if (t == 1023) offn[NN] = sums[1023];
  // batch offsets: 64-lane shuffle scan (first wave)
  if (t < 64) {
    int v = cntb[t];
    int incl = v;
    #pragma unroll
    for (int o = 1; o < 64; o <<= 1) {
      int x = __shfl_up(incl, o, 64);
      if (t >= o) incl += x;
    }
    int excl2 = incl - v;
    offb[t] = excl2;
    curb[t] = excl2;
    if (t == 63) offb[BB] = incl;
  }
}

// ---------------------------------------------------------------- scatter
// curb (64 bins) two-level: LDS hist -> one range-reserving global atomic per bin
// -> LDS rank. Kills the same 64-counter hot-line as kEncCount. Order within a
// bucket changes (irrelevant: aggregation is a sum).
__global__ __launch_bounds__(256) void kScatter(const int* __restrict__ src,
                                                const int* __restrict__ dst,
                                                const float* __restrict__ w,
                                                const int* __restrict__ bassign,
                                                int* curn, int* curb,
                                                long long* sedge, int* snode) {
  __shared__ int hb[64], rs[64], hc[64];
  int tt = threadIdx.x;
  if (tt < 64) { hb[tt] = 0; hc[tt] = 0; }
  __syncthreads();
  int t = blockIdx.x * 256 + tt;
  int b = -1;
  if (t < NN) { b = bassign[t]; atomicAdd(&hb[b], 1); }
  __syncthreads();
  if (tt < 64 && hb[tt] > 0) rs[tt] = atomicAdd(&curb[tt], hb[tt]);
  __syncthreads();
  if (t < NN) {
    int p = rs[b] + atomicAdd(&hc[b], 1);
    snode[p] = t;
  }
  if (t < EE) {
    int d = dst[t];
    int p = atomicAdd(&curn[d], 1);
    unsigned long long e = (unsigned long long)(unsigned)src[t]
                         | ((unsigned long long)(unsigned)__float_as_int(w[t]) << 32);
    sedge[p] = (long long)e;
  }
}

// ---------------------------------------------------------------- aggregation (XCD-sliced, 32 nodes/block)
// 8 feature slices of 32 cols; slice = blockIdx&7 -> per-XCD h hot set = 2.56MB (L2).
// Block = 32 consecutive nodes of one slice (grid 8*627=5016): amortizes offsets/
// staging/barriers 8x vs round-9's 4-node blocks (which were fixed-cost dominated:
// ~5.5 resident blocks, 28 serial drain rounds). 4 waves; wave w owns nodes w*8..w*8+7.
// Lane = eg*8+pc: one dwordx4 per lane serves 8 edges x 32 cols. Batch rows staged
// as weight-1.0 packed edges -> single unified gather loop. Full 32-wave occupancy.
#define ANPB 32     // nodes per block
#define ECAP 1024   // staged edges per chunk (8 KB)
__global__ __launch_bounds__(256) void kAgg(const float* __restrict__ h,
                                            const int* __restrict__ offn,
                                            const long long* __restrict__ sedge,
                                            const int* __restrict__ offb,
                                            const int* __restrict__ snode,
                                            float* __restrict__ hnv) {
  __shared__ __align__(16) long long Led[ECAP];
  __shared__ int Loff[ANPB + 1];
  int bid = blockIdx.x;
  int slice = bid & 7, group = bid >> 3;      // group 0..626
  int t = threadIdx.x;
  int w = t >> 6, lane = t & 63;
  int eg = lane >> 3;          // edge group 0..7
  int pc = lane & 7;           // float4 piece 0..7
  int colB = slice * 32 + pc * 4;
  bool isBatch = group < 2;                   // 2 blocks x 32 = 64 batch rows, first
  int first = isBatch ? group * ANPB : (group - 2) * ANPB;
  const int* off = isBatch ? offb : offn;
  if (t <= ANPB) Loff[t] = off[first + t];
  float4 acc[8];
  #pragma unroll
  for (int j = 0; j < 8; j++) acc[j] = make_float4(0.f, 0.f, 0.f, 0.f);
  __syncthreads();
  int s0 = Loff[0], e0 = Loff[ANPB];

  for (int base = s0; base < e0; base += ECAP) {
    int cnt = min(e0 - base, ECAP);
    // stage edges (batch rows as weight-1.0 packed edges)
    if (isBatch) {
      for (int i = t; i < cnt; i += 256)
        Led[i] = (long long)(0x3f800000ULL << 32) | (unsigned)snode[base + i];
    } else {
      for (int i = t; i < cnt; i += 256) Led[i] = sedge[base + i];
    }
    __syncthreads();
    #pragma unroll
    for (int j = 0; j < 8; j++) {
      int nd = w * 8 + j;
      int lo = max(Loff[nd], base), hi = min(Loff[nd + 1], base + cnt);
      for (int i = lo; i < hi; i += 8) {
        int idx = i + eg;
        long long ev = Led[min(idx, hi - 1) - base];
        float wgt = (idx < hi) ? __int_as_float((int)(ev >> 32)) : 0.f;
        unsigned srow = (unsigned)(ev & 0xffffffffLL);
        float4 v = *(const float4*)(h + (size_t)srow * DD + colB);
        acc[j].x = fmaf(wgt, v.x, acc[j].x);
        acc[j].y = fmaf(wgt, v.y, acc[j].y);
        acc[j].z = fmaf(wgt, v.z, acc[j].z);
        acc[j].w = fmaf(wgt, v.w, acc[j].w);
      }
    }
    __syncthreads();   // protect Led before next staging round
  }
  int dstBase = isBatch ? (NN + first) : first;
  #pragma unroll
  for (int j = 0; j < 8; j++) {
    #pragma unroll
    for (int o = 8; o < 64; o <<= 1) {
      acc[j].x += __shfl_xor(acc[j].x, o, 64);
      acc[j].y += __shfl_xor(acc[j].y, o, 64);
      acc[j].z += __shfl_xor(acc[j].z, o, 64);
      acc[j].w += __shfl_xor(acc[j].w, o, 64);
    }
    if (eg == 0)
      *(float4*)(hnv + (size_t)(dstBase + w * 8 + j) * DD + colB) = acc[j];
  }
}

// ---------------------------------------------------------------- MFMA dual-GEMM + fused l2norm
// hOut[r,:] = l2norm( relu( sum_k A'[r,k]*B'[k,c] + lb[c] ) ), A' = [h | hnv] (K=512).
// Tile: 32 rows x 256 cols (full width) per block; 4 waves of 32x64; grid = 627 (exact).
#define TRU 32
#define KC 32
__global__ __launch_bounds__(256) void kUpdM(const float* __restrict__ A,
                                             const float* __restrict__ Av,
                                             const short* __restrict__ Bth,
                                             const short* __restrict__ Btl,
                                             const float* __restrict__ lb,
                                             float* __restrict__ out) {
  __shared__ __align__(16) short Ah[TRU][KC];
  __shared__ __align__(16) short Al[TRU][KC];
  __shared__ __align__(16) short Bh[DD][KC];
  __shared__ __align__(16) short Bl[DD][KC];
  __shared__ float ssq[4][TRU];
  const int t = threadIdx.x;
  const int rb = blockIdx.x * TRU;
  const int wid = t >> 6;
  const int lane = t & 63;
  const int wc = wid * 64;         // wave col offset (4 waves cover 256 cols)
  const int m16 = lane & 15;
  const int kg = lane >> 4;        // 0..3

  floatx4 acc[2][4];
  #pragma unroll
  for (int ct = 0; ct < 4; ct++) {
    float b = lb[wc + ct * 16 + m16];
    #pragma unroll
    for (int rt = 0; rt < 2; rt++) acc[rt][ct] = (floatx4){b, b, b, b};
  }

  for (int kc = 0; kc < 512 / KC; ++kc) {
    const int k0 = kc * KC;
    const float* src = (k0 < DD) ? (A + k0) : (Av + (k0 - DD));
    // ---- stage A (fp32 -> hi/lo bf16), 32 rows x 32 k = 256 float4 (1/thread)
    {
      int r = t >> 3;              // 0..31
      int q = t & 7;               // float4 index within row
      float4 v = *(const float4*)(src + (size_t)(rb + r) * DD + q * 4);
      short s0 = f2bf(v.x), s1 = f2bf(v.y), s2 = f2bf(v.z), s3 = f2bf(v.w);
      short l0 = f2bf(v.x - bf2f(s0)), l1 = f2bf(v.y - bf2f(s1));
      short l2 = f2bf(v.z - bf2f(s2)), l3 = f2bf(v.w - bf2f(s3));
      uint2 whi, wlo;
      whi.x = (unsigned short)s0 | ((unsigned)(unsigned short)s1 << 16);
      whi.y = (unsigned short)s2 | ((unsigned)(unsigned short)s3 << 16);
      wlo.x = (unsigned short)l0 | ((unsigned)(unsigned short)l1 << 16);
      wlo.y = (unsigned short)l2 | ((unsigned)(unsigned short)l3 << 16);
      *(uint2*)&Ah[r][q * 4] = whi;
      *(uint2*)&Al[r][q * 4] = wlo;
    }
    // ---- stage B (pre-split bf16, straight copy), 256 n x 32 k per plane
    #pragma unroll
    for (int it = 0; it < 4; ++it) {
      int idx = t + it * 256;      // 0..1023
      int n = idx >> 2;            // 0..255
      int sg = idx & 3;            // 16B segment
      *(uint4*)&Bh[n][sg * 8] = *((const uint4*)(Bth + (size_t)n * 512 + k0) + sg);
      *(uint4*)&Bl[n][sg * 8] = *((const uint4*)(Btl + (size_t)n * 512 + k0) + sg);
    }
    __syncthreads();
    // ---- fragments + MFMA
    short8 af[2], al_[2], bf_[4], bl_[4];
    #pragma unroll
    for (int rt = 0; rt < 2; rt++) {
      af[rt]  = *(const short8*)&Ah[rt * 16 + m16][kg * 8];
      al_[rt] = *(const short8*)&Al[rt * 16 + m16][kg * 8];
    }
    #pragma unroll
    for (int ct = 0; ct < 4; ct++) {
      bf_[ct] = *(const short8*)&Bh[wc + ct * 16 + m16][kg * 8];
      bl_[ct] = *(const short8*)&Bl[wc + ct * 16 + m16][kg * 8];
    }
    #pragma unroll
    for (int rt = 0; rt < 2; rt++)
      #pragma unroll
      for (int ct = 0; ct < 4; ct++) {
        acc[rt][ct] = __builtin_amdgcn_mfma_f32_16x16x32_bf16(af[rt], bf_[ct], acc[rt][ct], 0, 0, 0);
        acc[rt][ct] = __builtin_amdgcn_mfma_f32_16x16x32_bf16(af[rt], bl_[ct], acc[rt][ct], 0, 0, 0);
        acc[rt][ct] = __builtin_amdgcn_mfma_f32_16x16x32_bf16(al_[rt], bf_[ct], acc[rt][ct], 0, 0, 0);
      }
    __syncthreads();
  }
  // ---- epilogue: relu + row l2norm + store (C/D: col=lane&15, row=(lane>>4)*4+reg)
  float p[2][4];
  #pragma unroll
  for (int rt = 0; rt < 2; rt++)
    #pragma unroll
    for (int reg = 0; reg < 4; reg++) {
      float s = 0.f;
      #pragma unroll
      for (int ct = 0; ct < 4; ct++) {
        float x = fmaxf(acc[rt][ct][reg], 0.f);
        s = fmaf(x, x, s);
      }
      p[rt][reg] = s;
    }
  #pragma unroll
  for (int o = 1; o < 16; o <<= 1)
    #pragma unroll
    for (int rt = 0; rt < 2; rt++)
      #pragma unroll
      for (int reg = 0; reg < 4; reg++)
        p[rt][reg] += __shfl_xor(p[rt][reg], o, 64);
  if (m16 == 0) {
    #pragma unroll
    for (int rt = 0; rt < 2; rt++)
      #pragma unroll
      for (int reg = 0; reg < 4; reg++)
        ssq[wid][rt * 16 + kg * 4 + reg] = p[rt][reg];
  }
  __syncthreads();
  #pragma unroll
  for (int rt = 0; rt < 2; rt++) {
    #pragma unroll
    for (int reg = 0; reg < 4; reg++) {
      int row = rt * 16 + kg * 4 + reg;
      float ss = ssq[0][row] + ssq[1][row] + ssq[2][row] + ssq[3][row];
      float inv = 1.f / fmaxf(sqrtf(ss), 1e-12f);
      #pragma unroll
      for (int ct = 0; ct < 4; ct++) {
        int col = wc + ct * 16 + m16;
        out[(size_t)(rb + row) * DD + col] = fmaxf(acc[rt][ct][reg], 0.f) * inv;
      }
    }
  }
}

// ---------------------------------------------------------------- decode
__global__ __launch_bounds__(256) void kDec(const float* __restrict__ h,
                                            const int* __restrict__ aidx,
                                            const float* __restrict__ W4,
                                            const float* __restrict__ W5,
                                            float* __restrict__ Q) {
  __shared__ float tmp[4];
  int b = blockIdx.x, j = threadIdx.x;
  float s = blockSum256(h[(size_t)(NN + b) * DD + j] * W4[j], tmp);
  int a = aidx[b];
  float za = h[(size_t)a * DD + j];
  float q = blockSum256(fmaxf(za * s, 0.f) * W5[j], tmp);
  if (j == 0) Q[b] = q;
}

// ---------------------------------------------------------------- launcher
extern "C" void kernel_launch(void* const* d_in, const int* in_sizes, int n_in,
                              void* d_out, int out_size, void* d_ws, size_t ws_size,
                              hipStream_t stream) {
  (void)in_sizes; (void)n_in; (void)out_size; (void)ws_size;
  const int*   edge_src = (const int*)d_in[0];
  const int*   edge_dst = (const int*)d_in[1];
  const float* edge_w   = (const float*)d_in[2];
  const int*   bassign  = (const int*)d_in[3];
  const int*   aidx     = (const int*)d_in[4];
  const float* Xf       = (const float*)d_in[5];
  const float* Xs       = (const float*)d_in[6];
  const float* W1       = (const float*)d_in[7];
  const float* W2       = (const float*)d_in[8];
  const float* W3       = (const float*)d_in[9];
  const float* linW     = (const float*)d_in[10];
  const float* linB     = (const float*)d_in[11];
  const float* W4       = (const float*)d_in[12];
  const float* W5       = (const float*)d_in[13];
  float* Q = (float*)d_out;

  char* base = (char*)d_ws;
  const size_t NB = (size_t)NT * DD * 4;   // rows include hs
  float* hA   = (float*)(base);
  float* hnv  = (float*)(base + NB);
  float* hB   = (float*)(base + 2 * NB);
  size_t o = 3 * NB;
  short* Bth  = (short*)(base + o); o += (size_t)DD * 512 * 2;
  short* Btl  = (short*)(base + o); o += (size_t)DD * 512 * 2;
  long long* sedge = (long long*)(base + o); o += (size_t)EE * 8;
  int*   snode= (int*)(base + o);   o += (size_t)NN * 4;
  int*   cntn = (int*)(base + o);   o += (size_t)NN * 4;
  int*   cntb = (int*)(base + o);   o += (size_t)BB * 4;   // contiguous with cntn
  int*   offn = (int*)(base + o);   o += (size_t)(NN + 4) * 4;
  int*   offb = (int*)(base + o);   o += (size_t)(BB + 4) * 4;
  int*   curn = (int*)(base + o);   o += (size_t)NN * 4;
  int*   curb = (int*)(base + o);   o += (size_t)BB * 4;

  hipMemsetAsync(cntn, 0, (size_t)(NN + BB) * 4, stream);

  kM<<<512, 256, 0, stream>>>(W2, W3, linW, Bth, Btl);
  kEncCount<<<NCB + NT / 4, 256, 0, stream>>>(Xf, Xs, W1, hA,
                                              edge_dst, bassign, cntn, cntb);
  kScan<<<1, 1024, 0, stream>>>(cntn, offn, curn, cntb, offb, curb);
  kScatter<<<(EE + 255) / 256, 256, 0, stream>>>(edge_src, edge_dst, edge_w, bassign,
                                                 curn, curb, sedge, snode);
  float* hc = hA;
  float* hn = hB;
  for (int d = 0; d < DEPTH; d++) {
    kAgg<<<8 * (NT / ANPB), 256, 0, stream>>>(hc, offn, sedge, offb, snode, hnv);
    kUpdM<<<NT / TRU, 256, 0, stream>>>(hc, hnv, Bth, Btl, linB, hn);
    float* sw2 = hc; hc = hn; hn = sw2;
  }
  kDec<<<BB, 256, 0, stream>>>(hc, aidx, W4, W5, Q);
}

// Round 11
// 405.930 us; speedup vs baseline: 2.4181x; 2.4181x over previous
//
#include <hip/hip_runtime.h>

#define NN 20000
#define EE 320000
#define BB 64
#define DD 256
#define DEPTH 3
#define NT (NN + BB)   // h rows + hs rows appended (NT = 20064 = 32*627 = 4*5016)

typedef __attribute__((ext_vector_type(8))) short short8;
typedef __attribute__((ext_vector_type(4))) float floatx4;

// ---------------------------------------------------------------- bf16 split helpers
__device__ __forceinline__ short f2bf(float x) {
  union { float f; unsigned u; } v; v.f = x;
  unsigned r = v.u + 0x7fffu + ((v.u >> 16) & 1u);  // RNE
  return (short)(r >> 16);
}
__device__ __forceinline__ float bf2f(short s) {
  union { unsigned u; float f; } v; v.u = ((unsigned)(unsigned short)s) << 16;
  return v.f;
}

// ---------------------------------------------------------------- reductions
__device__ __forceinline__ float blockSum256(float v, float* tmp) {
  #pragma unroll
  for (int o = 32; o > 0; o >>= 1) v += __shfl_down(v, o, 64);
  if ((threadIdx.x & 63) == 0) tmp[threadIdx.x >> 6] = v;
  __syncthreads();
  float r = tmp[0] + tmp[1] + tmp[2] + tmp[3];
  __syncthreads();
  return r;
}

// ---------------------------------------------------------------- M2/M3 -> split transposed B
__global__ __launch_bounds__(256) void kM(const float* __restrict__ W2,
                                          const float* __restrict__ W3,
                                          const float* __restrict__ linW,
                                          short* __restrict__ Bth,
                                          short* __restrict__ Btl) {
  int i = blockIdx.x & 255;
  bool second = blockIdx.x >= 256;
  const float* W = second ? W3 : W2;
  const float* L = linW + (second ? DD * DD : 0);
  int j = threadIdx.x;
  float acc = 0.f;
  #pragma unroll 4
  for (int k = 0; k < DD; k++) acc = fmaf(W[i * DD + k], L[k * DD + j], acc);
  short hi = f2bf(acc);
  short lo = f2bf(acc - bf2f(hi));
  int kk = second ? (DD + i) : i;
  Bth[(size_t)j * 512 + kk] = hi;
  Btl[(size_t)j * 512 + kk] = lo;
}

// ---------------------------------------------------------------- count (first) + encode (wave-per-row)
// cntb (64 bins) via LDS histogram: direct atomics on 64 ints = one hot L2 line,
// 20K serialized RMWs (round-9 evidence: kEncCount 47us @ VALU 5.8%).
#define NCB ((EE + 255) / 256)   // 1250 count blocks, scheduled first
__global__ __launch_bounds__(256) void kEncCount(const float* __restrict__ X,
                                                 const float* __restrict__ Xs,
                                                 const float* __restrict__ W1,
                                                 float* __restrict__ h,
                                                 const int* __restrict__ dst,
                                                 const int* __restrict__ bassign,
                                                 int* cntn, int* cntb) {
  __shared__ int hb[64];
  int bid = blockIdx.x, j = threadIdx.x;
  if (bid < NCB) {
    if (j < 64) hb[j] = 0;
    __syncthreads();
    int t = bid * 256 + j;
    if (t < EE) atomicAdd(&cntn[dst[t]], 1);
    if (t < NN) atomicAdd(&hb[bassign[t]], 1);   // LDS atomic
    __syncthreads();
    if (j < 64 && hb[j] > 0) atomicAdd(&cntb[j], hb[j]);
  } else {
    int r = (bid - NCB) * 4 + (j >> 6);     // wave-per-row
    int lane = j & 63, c0 = lane * 4;
    const float* x = (r < NN) ? (X + (size_t)r * 2) : (Xs + (size_t)(r - NN) * 2);
    float x0 = x[0], x1 = x[1];
    float4 wa = *(const float4*)(W1 + c0);
    float4 wb = *(const float4*)(W1 + DD + c0);
    float4 v;
    v.x = fmaxf(fmaf(x0, wa.x, x1 * wb.x), 0.f);
    v.y = fmaxf(fmaf(x0, wa.y, x1 * wb.y), 0.f);
    v.z = fmaxf(fmaf(x0, wa.z, x1 * wb.z), 0.f);
    v.w = fmaxf(fmaf(x0, wa.w, x1 * wb.w), 0.f);
    float ss = v.x * v.x + v.y * v.y + v.z * v.z + v.w * v.w;
    #pragma unroll
    for (int o = 1; o < 64; o <<= 1) ss += __shfl_xor(ss, o, 64);
    float inv = 1.f / fmaxf(sqrtf(ss), 1e-12f);
    v.x *= inv; v.y *= inv; v.z *= inv; v.w *= inv;
    *(float4*)(h + (size_t)r * DD + c0) = v;
  }
}

// ---------------------------------------------------------------- CSR scan
__global__ __launch_bounds__(1024) void kScan(const int* __restrict__ cntn,
                                              int* offn, int* curn,
                                              const int* __restrict__ cntb,
                                              int* offb, int* curb) {
  __shared__ int sums[1024];
  int t = threadIdx.x;
  const int CH = 20;  // 1024*20 = 20480 >= NN
  int base = t * CH;
  int local[CH];
  int s = 0;
  #pragma unroll
  for (int i = 0; i < CH; i++) {
    int idx = base + i;
    int v = (idx < NN) ? cntn[idx] : 0;
    local[i] = s;
    s += v;
  }
  sums[t] = s;
  __syncthreads();
  for (int o = 1; o < 1024; o <<= 1) {
    int x = (t >= o) ? sums[t - o] : 0;
    __syncthreads();
    sums[t] += x;
    __syncthreads();
  }
  int excl = sums[t] - s;
  #pragma unroll
  for (int i = 0; i < CH; i++) {
    int idx = base + i;
    if (idx < NN) {
      int o = excl + local[i];
      offn[idx] = o;
      curn[idx] = o;
    }
  }
  if (t == 1023) offn[NN] = sums[1023];
  // batch offsets: 64-lane shuffle scan (first wave)
  if (t < 64) {
    int v = cntb[t];
    int incl = v;
    #pragma unroll
    for (int o = 1; o < 64; o <<= 1) {
      int x = __shfl_up(incl, o, 64);
      if (t >= o) incl += x;
    }
    int excl2 = incl - v;
    offb[t] = excl2;
    curb[t] = excl2;
    if (t == 63) offb[BB] = incl;
  }
}

// ---------------------------------------------------------------- scatter
// curb (64 bins) two-level: LDS hist -> one range-reserving global atomic per bin
// -> LDS rank. Kills the 64-counter hot-line. Order within a bucket changes
// (irrelevant: aggregation is a sum).
__global__ __launch_bounds__(256) void kScatter(const int* __restrict__ src,
                                                const int* __restrict__ dst,
                                                const float* __restrict__ w,
                                                const int* __restrict__ bassign,
                                                int* curn, int* curb,
                                                long long* sedge, int* snode) {
  __shared__ int hb[64], rs[64], hc[64];
  int tt = threadIdx.x;
  if (tt < 64) { hb[tt] = 0; hc[tt] = 0; }
  __syncthreads();
  int t = blockIdx.x * 256 + tt;
  int b = -1;
  if (t < NN) { b = bassign[t]; atomicAdd(&hb[b], 1); }
  __syncthreads();
  if (tt < 64 && hb[tt] > 0) rs[tt] = atomicAdd(&curb[tt], hb[tt]);
  __syncthreads();
  if (t < NN) {
    int p = rs[b] + atomicAdd(&hc[b], 1);
    snode[p] = t;
  }
  if (t < EE) {
    int d = dst[t];
    int p = atomicAdd(&curn[d], 1);
    unsigned long long e = (unsigned long long)(unsigned)src[t]
                         | ((unsigned long long)(unsigned)__float_as_int(w[t]) << 32);
    sedge[p] = (long long)e;
  }
}

// ---------------------------------------------------------------- aggregation (XCD-sliced, float4 gathers)
// ROUND-9 KNOWN-GOOD STRUCTURE (47.5us). Round-10's 32-node blocks spilled the
// 8x float4 accumulator to scratch (VGPR_Count 28 < 32 acc floats) -> 239us.
// Keep acc at 1 float4/lane: block = 4 waves = 4 nodes; lane = eg*8+pc.
#define ECAP 1024   // staged edges per chunk (8 KB)
__global__ __launch_bounds__(256) void kAgg(const float* __restrict__ h,
                                            const int* __restrict__ offn,
                                            const long long* __restrict__ sedge,
                                            const int* __restrict__ offb,
                                            const int* __restrict__ snode,
                                            float* __restrict__ hnv) {
  __shared__ __align__(16) long long Led[ECAP];
  int bid = blockIdx.x;
  int slice = bid & 7, group = bid >> 3;      // group 0..5015
  int t = threadIdx.x;
  int w = t >> 6, lane = t & 63;
  int eg = lane >> 3;          // edge group 0..7
  int pc = lane & 7;           // float4 piece 0..7
  int colB = slice * 32 + pc * 4;
  float4 acc = make_float4(0.f, 0.f, 0.f, 0.f);

  if (group < 16) {
    // ---- batch rows: nodes 0..63, snode index list (weight 1)
    int b0 = group * 4;
    int s0 = offb[b0], e0 = offb[b0 + 4];
    int sW = offb[b0 + w], eW = offb[b0 + w + 1];
    int* Li = (int*)Led;
    for (int base = s0; base < e0; base += 2 * ECAP) {
      int cnt = min(e0 - base, 2 * ECAP);
      __syncthreads();
      for (int i = t; i < cnt; i += 256) Li[i] = snode[base + i];
      __syncthreads();
      int lo = max(sW, base), hi = min(eW, base + cnt);
      for (int i = lo; i < hi; i += 8) {
        int idx = i + eg;
        int nrow = Li[min(idx, hi - 1) - base];
        float wgt = (idx < hi) ? 1.f : 0.f;
        float4 v = *(const float4*)(h + (size_t)nrow * DD + colB);
        acc.x = fmaf(wgt, v.x, acc.x);
        acc.y = fmaf(wgt, v.y, acc.y);
        acc.z = fmaf(wgt, v.z, acc.z);
        acc.w = fmaf(wgt, v.w, acc.w);
      }
    }
    #pragma unroll
    for (int o = 8; o < 64; o <<= 1) {
      acc.x += __shfl_xor(acc.x, o, 64);
      acc.y += __shfl_xor(acc.y, o, 64);
      acc.z += __shfl_xor(acc.z, o, 64);
      acc.w += __shfl_xor(acc.w, o, 64);
    }
    if (eg == 0) *(float4*)(hnv + (size_t)(NN + b0 + w) * DD + colB) = acc;
  } else {
    // ---- edge nodes
    int first = group * 4 - BB;                // node range [first, first+4)
    int s0 = offn[first], e0 = offn[first + 4];
    int sW = offn[first + w], eW = offn[first + w + 1];
    for (int base = s0; base < e0; base += ECAP) {
      int cnt = min(e0 - base, ECAP);
      __syncthreads();
      for (int i = t; i < cnt; i += 256) Led[i] = sedge[base + i];
      __syncthreads();
      int lo = max(sW, base), hi = min(eW, base + cnt);
      for (int i = lo; i < hi; i += 8) {
        int idx = i + eg;
        long long ev = Led[min(idx, hi - 1) - base];
        float wgt = (idx < hi) ? __int_as_float((int)(ev >> 32)) : 0.f;
        unsigned srow = (unsigned)(ev & 0xffffffffLL);
        float4 v = *(const float4*)(h + (size_t)srow * DD + colB);
        acc.x = fmaf(wgt, v.x, acc.x);
        acc.y = fmaf(wgt, v.y, acc.y);
        acc.z = fmaf(wgt, v.z, acc.z);
        acc.w = fmaf(wgt, v.w, acc.w);
      }
    }
    #pragma unroll
    for (int o = 8; o < 64; o <<= 1) {
      acc.x += __shfl_xor(acc.x, o, 64);
      acc.y += __shfl_xor(acc.y, o, 64);
      acc.z += __shfl_xor(acc.z, o, 64);
      acc.w += __shfl_xor(acc.w, o, 64);
    }
    if (eg == 0) *(float4*)(hnv + (size_t)(first + w) * DD + colB) = acc;
  }
}

// ---------------------------------------------------------------- MFMA dual-GEMM + fused l2norm
// hOut[r,:] = l2norm( relu( sum_k A'[r,k]*B'[k,c] + lb[c] ) ), A' = [h | hnv] (K=512).
// Tile: 32 rows x 256 cols (full width) per block; 4 waves of 32x64; grid = 627 (exact).
#define TRU 32
#define KC 32
__global__ __launch_bounds__(256) void kUpdM(const float* __restrict__ A,
                                             const float* __restrict__ Av,
                                             const short* __restrict__ Bth,
                                             const short* __restrict__ Btl,
                                             const float* __restrict__ lb,
                                             float* __restrict__ out) {
  __shared__ __align__(16) short Ah[TRU][KC];
  __shared__ __align__(16) short Al[TRU][KC];
  __shared__ __align__(16) short Bh[DD][KC];
  __shared__ __align__(16) short Bl[DD][KC];
  __shared__ float ssq[4][TRU];
  const int t = threadIdx.x;
  const int rb = blockIdx.x * TRU;
  const int wid = t >> 6;
  const int lane = t & 63;
  const int wc = wid * 64;         // wave col offset (4 waves cover 256 cols)
  const int m16 = lane & 15;
  const int kg = lane >> 4;        // 0..3

  floatx4 acc[2][4];
  #pragma unroll
  for (int ct = 0; ct < 4; ct++) {
    float b = lb[wc + ct * 16 + m16];
    #pragma unroll
    for (int rt = 0; rt < 2; rt++) acc[rt][ct] = (floatx4){b, b, b, b};
  }

  for (int kc = 0; kc < 512 / KC; ++kc) {
    const int k0 = kc * KC;
    const float* src = (k0 < DD) ? (A + k0) : (Av + (k0 - DD));
    // ---- stage A (fp32 -> hi/lo bf16), 32 rows x 32 k = 256 float4 (1/thread)
    {
      int r = t >> 3;              // 0..31
      int q = t & 7;               // float4 index within row
      float4 v = *(const float4*)(src + (size_t)(rb + r) * DD + q * 4);
      short s0 = f2bf(v.x), s1 = f2bf(v.y), s2 = f2bf(v.z), s3 = f2bf(v.w);
      short l0 = f2bf(v.x - bf2f(s0)), l1 = f2bf(v.y - bf2f(s1));
      short l2 = f2bf(v.z - bf2f(s2)), l3 = f2bf(v.w - bf2f(s3));
      uint2 whi, wlo;
      whi.x = (unsigned short)s0 | ((unsigned)(unsigned short)s1 << 16);
      whi.y = (unsigned short)s2 | ((unsigned)(unsigned short)s3 << 16);
      wlo.x = (unsigned short)l0 | ((unsigned)(unsigned short)l1 << 16);
      wlo.y = (unsigned short)l2 | ((unsigned)(unsigned short)l3 << 16);
      *(uint2*)&Ah[r][q * 4] = whi;
      *(uint2*)&Al[r][q * 4] = wlo;
    }
    // ---- stage B (pre-split bf16, straight copy), 256 n x 32 k per plane
    #pragma unroll
    for (int it = 0; it < 4; ++it) {
      int idx = t + it * 256;      // 0..1023
      int n = idx >> 2;            // 0..255
      int sg = idx & 3;            // 16B segment
      *(uint4*)&Bh[n][sg * 8] = *((const uint4*)(Bth + (size_t)n * 512 + k0) + sg);
      *(uint4*)&Bl[n][sg * 8] = *((const uint4*)(Btl + (size_t)n * 512 + k0) + sg);
    }
    __syncthreads();
    // ---- fragments + MFMA
    short8 af[2], al_[2], bf_[4], bl_[4];
    #pragma unroll
    for (int rt = 0; rt < 2; rt++) {
      af[rt]  = *(const short8*)&Ah[rt * 16 + m16][kg * 8];
      al_[rt] = *(const short8*)&Al[rt * 16 + m16][kg * 8];
    }
    #pragma unroll
    for (int ct = 0; ct < 4; ct++) {
      bf_[ct] = *(const short8*)&Bh[wc + ct * 16 + m16][kg * 8];
      bl_[ct] = *(const short8*)&Bl[wc + ct * 16 + m16][kg * 8];
    }
    #pragma unroll
    for (int rt = 0; rt < 2; rt++)
      #pragma unroll
      for (int ct = 0; ct < 4; ct++) {
        acc[rt][ct] = __builtin_amdgcn_mfma_f32_16x16x32_bf16(af[rt], bf_[ct], acc[rt][ct], 0, 0, 0);
        acc[rt][ct] = __builtin_amdgcn_mfma_f32_16x16x32_bf16(af[rt], bl_[ct], acc[rt][ct], 0, 0, 0);
        acc[rt][ct] = __builtin_amdgcn_mfma_f32_16x16x32_bf16(al_[rt], bf_[ct], acc[rt][ct], 0, 0, 0);
      }
    __syncthreads();
  }
  // ---- epilogue: relu + row l2norm + store (C/D: col=lane&15, row=(lane>>4)*4+reg)
  float p[2][4];
  #pragma unroll
  for (int rt = 0; rt < 2; rt++)
    #pragma unroll
    for (int reg = 0; reg < 4; reg++) {
      float s = 0.f;
      #pragma unroll
      for (int ct = 0; ct < 4; ct++) {
        float x = fmaxf(acc[rt][ct][reg], 0.f);
        s = fmaf(x, x, s);
      }
      p[rt][reg] = s;
    }
  #pragma unroll
  for (int o = 1; o < 16; o <<= 1)
    #pragma unroll
    for (int rt = 0; rt < 2; rt++)
      #pragma unroll
      for (int reg = 0; reg < 4; reg++)
        p[rt][reg] += __shfl_xor(p[rt][reg], o, 64);
  if (m16 == 0) {
    #pragma unroll
    for (int rt = 0; rt < 2; rt++)
      #pragma unroll
      for (int reg = 0; reg < 4; reg++)
        ssq[wid][rt * 16 + kg * 4 + reg] = p[rt][reg];
  }
  __syncthreads();
  #pragma unroll
  for (int rt = 0; rt < 2; rt++) {
    #pragma unroll
    for (int reg = 0; reg < 4; reg++) {
      int row = rt * 16 + kg * 4 + reg;
      float ss = ssq[0][row] + ssq[1][row] + ssq[2][row] + ssq[3][row];
      float inv = 1.f / fmaxf(sqrtf(ss), 1e-12f);
      #pragma unroll
      for (int ct = 0; ct < 4; ct++) {
        int col = wc + ct * 16 + m16;
        out[(size_t)(rb + row) * DD + col] = fmaxf(acc[rt][ct][reg], 0.f) * inv;
      }
    }
  }
}

// ---------------------------------------------------------------- decode
__global__ __launch_bounds__(256) void kDec(const float* __restrict__ h,
                                            const int* __restrict__ aidx,
                                            const float* __restrict__ W4,
                                            const float* __restrict__ W5,
                                            float* __restrict__ Q) {
  __shared__ float tmp[4];
  int b = blockIdx.x, j = threadIdx.x;
  float s = blockSum256(h[(size_t)(NN + b) * DD + j] * W4[j], tmp);
  int a = aidx[b];
  float za = h[(size_t)a * DD + j];
  float q = blockSum256(fmaxf(za * s, 0.f) * W5[j], tmp);
  if (j == 0) Q[b] = q;
}

// ---------------------------------------------------------------- launcher
extern "C" void kernel_launch(void* const* d_in, const int* in_sizes, int n_in,
                              void* d_out, int out_size, void* d_ws, size_t ws_size,
                              hipStream_t stream) {
  (void)in_sizes; (void)n_in; (void)out_size; (void)ws_size;
  const int*   edge_src = (const int*)d_in[0];
  const int*   edge_dst = (const int*)d_in[1];
  const float* edge_w   = (const float*)d_in[2];
  const int*   bassign  = (const int*)d_in[3];
  const int*   aidx     = (const int*)d_in[4];
  const float* Xf       = (const float*)d_in[5];
  const float* Xs       = (const float*)d_in[6];
  const float* W1       = (const float*)d_in[7];
  const float* W2       = (const float*)d_in[8];
  const float* W3       = (const float*)d_in[9];
  const float* linW     = (const float*)d_in[10];
  const float* linB     = (const float*)d_in[11];
  const float* W4       = (const float*)d_in[12];
  const float* W5       = (const float*)d_in[13];
  float* Q = (float*)d_out;

  char* base = (char*)d_ws;
  const size_t NB = (size_t)NT * DD * 4;   // rows include hs
  float* hA   = (float*)(base);
  float* hnv  = (float*)(base + NB);
  float* hB   = (float*)(base + 2 * NB);
  size_t o = 3 * NB;
  short* Bth  = (short*)(base + o); o += (size_t)DD * 512 * 2;
  short* Btl  = (short*)(base + o); o += (size_t)DD * 512 * 2;
  long long* sedge = (long long*)(base + o); o += (size_t)EE * 8;
  int*   snode= (int*)(base + o);   o += (size_t)NN * 4;
  int*   cntn = (int*)(base + o);   o += (size_t)NN * 4;
  int*   cntb = (int*)(base + o);   o += (size_t)BB * 4;   // contiguous with cntn
  int*   offn = (int*)(base + o);   o += (size_t)(NN + 4) * 4;
  int*   offb = (int*)(base + o);   o += (size_t)(BB + 4) * 4;
  int*   curn = (int*)(base + o);   o += (size_t)NN * 4;
  int*   curb = (int*)(base + o);   o += (size_t)BB * 4;

  hipMemsetAsync(cntn, 0, (size_t)(NN + BB) * 4, stream);

  kM<<<512, 256, 0, stream>>>(W2, W3, linW, Bth, Btl);
  kEncCount<<<NCB + NT / 4, 256, 0, stream>>>(Xf, Xs, W1, hA,
                                              edge_dst, bassign, cntn, cntb);
  kScan<<<1, 1024, 0, stream>>>(cntn, offn, curn, cntb, offb, curb);
  kScatter<<<(EE + 255) / 256, 256, 0, stream>>>(edge_src, edge_dst, edge_w, bassign,
                                                 curn, curb, sedge, snode);
  float* hc = hA;
  float* hn = hB;
  for (int d = 0; d < DEPTH; d++) {
    kAgg<<<8 * (NT / 4), 256, 0, stream>>>(hc, offn, sedge, offb, snode, hnv);
    kUpdM<<<NT / TRU, 256, 0, stream>>>(hc, hnv, Bth, Btl, linB, hn);
    float* sw2 = hc; hc = hn; hn = sw2;
  }
  kDec<<<BB, 256, 0, stream>>>(hc, aidx, W4, W5, Q);
}

// Round 12
// 395.763 us; speedup vs baseline: 2.4802x; 1.0257x over previous
//
#include <hip/hip_runtime.h>

#define NN 20000
#define EE 320000
#define BB 64
#define DD 256
#define DEPTH 3
#define NT (NN + BB)   // h rows + hs rows appended (NT = 20064 = 32*627 = 8*2508)

typedef __attribute__((ext_vector_type(8))) short short8;
typedef __attribute__((ext_vector_type(4))) float floatx4;

// ---------------------------------------------------------------- bf16 split helpers
__device__ __forceinline__ short f2bf(float x) {
  union { float f; unsigned u; } v; v.f = x;
  unsigned r = v.u + 0x7fffu + ((v.u >> 16) & 1u);  // RNE
  return (short)(r >> 16);
}
__device__ __forceinline__ float bf2f(short s) {
  union { unsigned u; float f; } v; v.u = ((unsigned)(unsigned short)s) << 16;
  return v.f;
}

// ---------------------------------------------------------------- reductions
__device__ __forceinline__ float blockSum256(float v, float* tmp) {
  #pragma unroll
  for (int o = 32; o > 0; o >>= 1) v += __shfl_down(v, o, 64);
  if ((threadIdx.x & 63) == 0) tmp[threadIdx.x >> 6] = v;
  __syncthreads();
  float r = tmp[0] + tmp[1] + tmp[2] + tmp[3];
  __syncthreads();
  return r;
}

// ---------------------------------------------------------------- count + kM + encode (fused)
// Block ranges: [0,NCB) degree counts; [NCB,NCB+512) B-matrix build; rest encode.
// cntb via LDS histogram (round-9 evidence: 20K RMWs on one 64-int line = 47us).
#define NCB ((EE + 255) / 256)   // 1250 count blocks, scheduled first
__global__ __launch_bounds__(256) void kEncCount(const float* __restrict__ X,
                                                 const float* __restrict__ Xs,
                                                 const float* __restrict__ W1,
                                                 float* __restrict__ h,
                                                 const int* __restrict__ dst,
                                                 const int* __restrict__ bassign,
                                                 int* cntn, int* cntb,
                                                 const float* __restrict__ W2,
                                                 const float* __restrict__ W3,
                                                 const float* __restrict__ linW,
                                                 short* __restrict__ Bth,
                                                 short* __restrict__ Btl) {
  __shared__ int hb[64];
  int bid = blockIdx.x, j = threadIdx.x;
  if (bid < NCB) {
    if (j < 64) hb[j] = 0;
    __syncthreads();
    int t = bid * 256 + j;
    if (t < EE) atomicAdd(&cntn[dst[t]], 1);
    if (t < NN) atomicAdd(&hb[bassign[t]], 1);   // LDS atomic
    __syncthreads();
    if (j < 64 && hb[j] > 0) atomicAdd(&cntb[j], hb[j]);
  } else if (bid < NCB + 512) {
    // ---- M2 = W2 @ linW[0:256,:], M3 = W3 @ linW[256:512,:], split-transposed
    int i = (bid - NCB) & 255;
    bool second = (bid - NCB) >= 256;
    const float* W = second ? W3 : W2;
    const float* L = linW + (second ? DD * DD : 0);
    float acc = 0.f;
    #pragma unroll 4
    for (int k = 0; k < DD; k++) acc = fmaf(W[i * DD + k], L[k * DD + j], acc);
    short hi = f2bf(acc);
    short lo = f2bf(acc - bf2f(hi));
    int kk = second ? (DD + i) : i;
    Bth[(size_t)j * 512 + kk] = hi;
    Btl[(size_t)j * 512 + kk] = lo;
  } else {
    int r = (bid - NCB - 512) * 4 + (j >> 6);     // wave-per-row
    int lane = j & 63, c0 = lane * 4;
    const float* x = (r < NN) ? (X + (size_t)r * 2) : (Xs + (size_t)(r - NN) * 2);
    float x0 = x[0], x1 = x[1];
    float4 wa = *(const float4*)(W1 + c0);
    float4 wb = *(const float4*)(W1 + DD + c0);
    float4 v;
    v.x = fmaxf(fmaf(x0, wa.x, x1 * wb.x), 0.f);
    v.y = fmaxf(fmaf(x0, wa.y, x1 * wb.y), 0.f);
    v.z = fmaxf(fmaf(x0, wa.z, x1 * wb.z), 0.f);
    v.w = fmaxf(fmaf(x0, wa.w, x1 * wb.w), 0.f);
    float ss = v.x * v.x + v.y * v.y + v.z * v.z + v.w * v.w;
    #pragma unroll
    for (int o = 1; o < 64; o <<= 1) ss += __shfl_xor(ss, o, 64);
    float inv = 1.f / fmaxf(sqrtf(ss), 1e-12f);
    v.x *= inv; v.y *= inv; v.z *= inv; v.w *= inv;
    *(float4*)(h + (size_t)r * DD + c0) = v;
  }
}

// ---------------------------------------------------------------- CSR scan
__global__ __launch_bounds__(1024) void kScan(const int* __restrict__ cntn,
                                              int* offn, int* curn,
                                              const int* __restrict__ cntb,
                                              int* offb, int* curb) {
  __shared__ int sums[1024];
  int t = threadIdx.x;
  const int CH = 20;  // 1024*20 = 20480 >= NN
  int base = t * CH;
  int local[CH];
  int s = 0;
  #pragma unroll
  for (int i = 0; i < CH; i++) {
    int idx = base + i;
    int v = (idx < NN) ? cntn[idx] : 0;
    local[i] = s;
    s += v;
  }
  sums[t] = s;
  __syncthreads();
  for (int o = 1; o < 1024; o <<= 1) {
    int x = (t >= o) ? sums[t - o] : 0;
    __syncthreads();
    sums[t] += x;
    __syncthreads();
  }
  int excl = sums[t] - s;
  #pragma unroll
  for (int i = 0; i < CH; i++) {
    int idx = base + i;
    if (idx < NN) {
      int o = excl + local[i];
      offn[idx] = o;
      curn[idx] = o;
    }
  }
  if (t == 1023) offn[NN] = sums[1023];
  // batch offsets: 64-lane shuffle scan (first wave)
  if (t < 64) {
    int v = cntb[t];
    int incl = v;
    #pragma unroll
    for (int o = 1; o < 64; o <<= 1) {
      int x = __shfl_up(incl, o, 64);
      if (t >= o) incl += x;
    }
    int excl2 = incl - v;
    offb[t] = excl2;
    curb[t] = excl2;
    if (t == 63) offb[BB] = incl;
  }
}

// ---------------------------------------------------------------- scatter
// curb two-level: LDS hist -> one range-reserving global atomic per bin -> LDS rank.
__global__ __launch_bounds__(256) void kScatter(const int* __restrict__ src,
                                                const int* __restrict__ dst,
                                                const float* __restrict__ w,
                                                const int* __restrict__ bassign,
                                                int* curn, int* curb,
                                                long long* sedge, int* snode) {
  __shared__ int hb[64], rs[64], hc[64];
  int tt = threadIdx.x;
  if (tt < 64) { hb[tt] = 0; hc[tt] = 0; }
  __syncthreads();
  int t = blockIdx.x * 256 + tt;
  int b = -1;
  if (t < NN) { b = bassign[t]; atomicAdd(&hb[b], 1); }
  __syncthreads();
  if (tt < 64 && hb[tt] > 0) rs[tt] = atomicAdd(&curb[tt], hb[tt]);
  __syncthreads();
  if (t < NN) {
    int p = rs[b] + atomicAdd(&hc[b], 1);
    snode[p] = t;
  }
  if (t < EE) {
    int d = dst[t];
    int p = atomicAdd(&curn[d], 1);
    unsigned long long e = (unsigned long long)(unsigned)src[t]
                         | ((unsigned long long)(unsigned)__float_as_int(w[t]) << 32);
    sedge[p] = (long long)e;
  }
}

// ---------------------------------------------------------------- aggregation (XCD-sliced, 8 waves = 8 nodes)
// 8 feature slices of 32 cols; slice = blockIdx&7 -> per-XCD h hot set 2.56MB (L2).
// Block = 512 threads = 8 waves = 8 nodes: amortizes offsets/staging/barriers 2x vs
// round-9's 4-node blocks WITHOUT touching per-lane registers (round-10's 8-node-
// per-wave acc[8] spilled to scratch: VGPR 28, 239us). acc stays 1 float4/lane.
// Inner loop: 16 edges/iter, two independent clamped gathers in flight per lane.
#define ECAP 1024   // staged edges per chunk (8 KB)
__global__ __launch_bounds__(512) void kAgg(const float* __restrict__ h,
                                            const int* __restrict__ offn,
                                            const long long* __restrict__ sedge,
                                            const int* __restrict__ offb,
                                            const int* __restrict__ snode,
                                            float* __restrict__ hnv) {
  __shared__ __align__(16) long long Led[ECAP];
  int bid = blockIdx.x;
  int slice = bid & 7, group = bid >> 3;      // group 0..2507
  int t = threadIdx.x;
  int w = t >> 6, lane = t & 63;
  int eg = lane >> 3;          // edge group 0..7
  int pc = lane & 7;           // float4 piece 0..7
  int colB = slice * 32 + pc * 4;
  float4 acc = make_float4(0.f, 0.f, 0.f, 0.f);

  if (group < 8) {
    // ---- batch rows: nodes 0..63 (8 per block), snode index list (weight 1)
    int b0 = group * 8;
    int s0 = offb[b0], e0 = offb[b0 + 8];
    int sW = offb[b0 + w], eW = offb[b0 + w + 1];
    int* Li = (int*)Led;
    for (int base = s0; base < e0; base += 2 * ECAP) {
      int cnt = min(e0 - base, 2 * ECAP);
      __syncthreads();
      for (int i = t; i < cnt; i += 512) Li[i] = snode[base + i];
      __syncthreads();
      int lo = max(sW, base), hi = min(eW, base + cnt);
      for (int i = lo; i < hi; i += 16) {
        int i0 = i + eg, i1 = i + 8 + eg;
        int n0 = Li[min(i0, hi - 1) - base];
        int n1 = Li[min(i1, hi - 1) - base];
        float w0 = (i0 < hi) ? 1.f : 0.f;
        float w1 = (i1 < hi) ? 1.f : 0.f;
        float4 v0 = *(const float4*)(h + (size_t)n0 * DD + colB);
        float4 v1 = *(const float4*)(h + (size_t)n1 * DD + colB);
        acc.x = fmaf(w0, v0.x, fmaf(w1, v1.x, acc.x));
        acc.y = fmaf(w0, v0.y, fmaf(w1, v1.y, acc.y));
        acc.z = fmaf(w0, v0.z, fmaf(w1, v1.z, acc.z));
        acc.w = fmaf(w0, v0.w, fmaf(w1, v1.w, acc.w));
      }
    }
    #pragma unroll
    for (int o = 8; o < 64; o <<= 1) {
      acc.x += __shfl_xor(acc.x, o, 64);
      acc.y += __shfl_xor(acc.y, o, 64);
      acc.z += __shfl_xor(acc.z, o, 64);
      acc.w += __shfl_xor(acc.w, o, 64);
    }
    if (eg == 0) *(float4*)(hnv + (size_t)(NN + b0 + w) * DD + colB) = acc;
  } else {
    // ---- edge nodes, 8 per block
    int first = (group - 8) * 8;
    int s0 = offn[first], e0 = offn[first + 8];
    int sW = offn[first + w], eW = offn[first + w + 1];
    for (int base = s0; base < e0; base += ECAP) {
      int cnt = min(e0 - base, ECAP);
      __syncthreads();
      for (int i = t; i < cnt; i += 512) Led[i] = sedge[base + i];
      __syncthreads();
      int lo = max(sW, base), hi = min(eW, base + cnt);
      for (int i = lo; i < hi; i += 16) {
        int i0 = i + eg, i1 = i + 8 + eg;
        long long e0v = Led[min(i0, hi - 1) - base];
        long long e1v = Led[min(i1, hi - 1) - base];
        float w0 = (i0 < hi) ? __int_as_float((int)(e0v >> 32)) : 0.f;
        float w1 = (i1 < hi) ? __int_as_float((int)(e1v >> 32)) : 0.f;
        unsigned r0 = (unsigned)(e0v & 0xffffffffLL);
        unsigned r1 = (unsigned)(e1v & 0xffffffffLL);
        float4 v0 = *(const float4*)(h + (size_t)r0 * DD + colB);
        float4 v1 = *(const float4*)(h + (size_t)r1 * DD + colB);
        acc.x = fmaf(w0, v0.x, fmaf(w1, v1.x, acc.x));
        acc.y = fmaf(w0, v0.y, fmaf(w1, v1.y, acc.y));
        acc.z = fmaf(w0, v0.z, fmaf(w1, v1.z, acc.z));
        acc.w = fmaf(w0, v0.w, fmaf(w1, v1.w, acc.w));
      }
    }
    #pragma unroll
    for (int o = 8; o < 64; o <<= 1) {
      acc.x += __shfl_xor(acc.x, o, 64);
      acc.y += __shfl_xor(acc.y, o, 64);
      acc.z += __shfl_xor(acc.z, o, 64);
      acc.w += __shfl_xor(acc.w, o, 64);
    }
    if (eg == 0) *(float4*)(hnv + (size_t)(first + w) * DD + colB) = acc;
  }
}

// ---------------------------------------------------------------- MFMA dual-GEMM + fused l2norm
// hOut[r,:] = l2norm( relu( sum_k A'[r,k]*B'[k,c] + lb[c] ) ), A' = [h | hnv] (K=512).
// Tile: 32 rows x 256 cols (full width) per block; 4 waves of 32x64; grid = 627 (exact).
#define TRU 32
#define KC 32
__global__ __launch_bounds__(256) void kUpdM(const float* __restrict__ A,
                                             const float* __restrict__ Av,
                                             const short* __restrict__ Bth,
                                             const short* __restrict__ Btl,
                                             const float* __restrict__ lb,
                                             float* __restrict__ out) {
  __shared__ __align__(16) short Ah[TRU][KC];
  __shared__ __align__(16) short Al[TRU][KC];
  __shared__ __align__(16) short Bh[DD][KC];
  __shared__ __align__(16) short Bl[DD][KC];
  __shared__ float ssq[4][TRU];
  const int t = threadIdx.x;
  const int rb = blockIdx.x * TRU;
  const int wid = t >> 6;
  const int lane = t & 63;
  const int wc = wid * 64;         // wave col offset (4 waves cover 256 cols)
  const int m16 = lane & 15;
  const int kg = lane >> 4;        // 0..3

  floatx4 acc[2][4];
  #pragma unroll
  for (int ct = 0; ct < 4; ct++) {
    float b = lb[wc + ct * 16 + m16];
    #pragma unroll
    for (int rt = 0; rt < 2; rt++) acc[rt][ct] = (floatx4){b, b, b, b};
  }

  for (int kc = 0; kc < 512 / KC; ++kc) {
    const int k0 = kc * KC;
    const float* src = (k0 < DD) ? (A + k0) : (Av + (k0 - DD));
    // ---- stage A (fp32 -> hi/lo bf16), 32 rows x 32 k = 256 float4 (1/thread)
    {
      int r = t >> 3;              // 0..31
      int q = t & 7;               // float4 index within row
      float4 v = *(const float4*)(src + (size_t)(rb + r) * DD + q * 4);
      short s0 = f2bf(v.x), s1 = f2bf(v.y), s2 = f2bf(v.z), s3 = f2bf(v.w);
      short l0 = f2bf(v.x - bf2f(s0)), l1 = f2bf(v.y - bf2f(s1));
      short l2 = f2bf(v.z - bf2f(s2)), l3 = f2bf(v.w - bf2f(s3));
      uint2 whi, wlo;
      whi.x = (unsigned short)s0 | ((unsigned)(unsigned short)s1 << 16);
      whi.y = (unsigned short)s2 | ((unsigned)(unsigned short)s3 << 16);
      wlo.x = (unsigned short)l0 | ((unsigned)(unsigned short)l1 << 16);
      wlo.y = (unsigned short)l2 | ((unsigned)(unsigned short)l3 << 16);
      *(uint2*)&Ah[r][q * 4] = whi;
      *(uint2*)&Al[r][q * 4] = wlo;
    }
    // ---- stage B (pre-split bf16, straight copy), 256 n x 32 k per plane
    #pragma unroll
    for (int it = 0; it < 4; ++it) {
      int idx = t + it * 256;      // 0..1023
      int n = idx >> 2;            // 0..255
      int sg = idx & 3;            // 16B segment
      *(uint4*)&Bh[n][sg * 8] = *((const uint4*)(Bth + (size_t)n * 512 + k0) + sg);
      *(uint4*)&Bl[n][sg * 8] = *((const uint4*)(Btl + (size_t)n * 512 + k0) + sg);
    }
    __syncthreads();
    // ---- fragments + MFMA
    short8 af[2], al_[2], bf_[4], bl_[4];
    #pragma unroll
    for (int rt = 0; rt < 2; rt++) {
      af[rt]  = *(const short8*)&Ah[rt * 16 + m16][kg * 8];
      al_[rt] = *(const short8*)&Al[rt * 16 + m16][kg * 8];
    }
    #pragma unroll
    for (int ct = 0; ct < 4; ct++) {
      bf_[ct] = *(const short8*)&Bh[wc + ct * 16 + m16][kg * 8];
      bl_[ct] = *(const short8*)&Bl[wc + ct * 16 + m16][kg * 8];
    }
    #pragma unroll
    for (int rt = 0; rt < 2; rt++)
      #pragma unroll
      for (int ct = 0; ct < 4; ct++) {
        acc[rt][ct] = __builtin_amdgcn_mfma_f32_16x16x32_bf16(af[rt], bf_[ct], acc[rt][ct], 0, 0, 0);
        acc[rt][ct] = __builtin_amdgcn_mfma_f32_16x16x32_bf16(af[rt], bl_[ct], acc[rt][ct], 0, 0, 0);
        acc[rt][ct] = __builtin_amdgcn_mfma_f32_16x16x32_bf16(al_[rt], bf_[ct], acc[rt][ct], 0, 0, 0);
      }
    __syncthreads();
  }
  // ---- epilogue: relu + row l2norm + store (C/D: col=lane&15, row=(lane>>4)*4+reg)
  float p[2][4];
  #pragma unroll
  for (int rt = 0; rt < 2; rt++)
    #pragma unroll
    for (int reg = 0; reg < 4; reg++) {
      float s = 0.f;
      #pragma unroll
      for (int ct = 0; ct < 4; ct++) {
        float x = fmaxf(acc[rt][ct][reg], 0.f);
        s = fmaf(x, x, s);
      }
      p[rt][reg] = s;
    }
  #pragma unroll
  for (int o = 1; o < 16; o <<= 1)
    #pragma unroll
    for (int rt = 0; rt < 2; rt++)
      #pragma unroll
      for (int reg = 0; reg < 4; reg++)
        p[rt][reg] += __shfl_xor(p[rt][reg], o, 64);
  if (m16 == 0) {
    #pragma unroll
    for (int rt = 0; rt < 2; rt++)
      #pragma unroll
      for (int reg = 0; reg < 4; reg++)
        ssq[wid][rt * 16 + kg * 4 + reg] = p[rt][reg];
  }
  __syncthreads();
  #pragma unroll
  for (int rt = 0; rt < 2; rt++) {
    #pragma unroll
    for (int reg = 0; reg < 4; reg++) {
      int row = rt * 16 + kg * 4 + reg;
      float ss = ssq[0][row] + ssq[1][row] + ssq[2][row] + ssq[3][row];
      float inv = 1.f / fmaxf(sqrtf(ss), 1e-12f);
      #pragma unroll
      for (int ct = 0; ct < 4; ct++) {
        int col = wc + ct * 16 + m16;
        out[(size_t)(rb + row) * DD + col] = fmaxf(acc[rt][ct][reg], 0.f) * inv;
      }
    }
  }
}

// ---------------------------------------------------------------- decode
__global__ __launch_bounds__(256) void kDec(const float* __restrict__ h,
                                            const int* __restrict__ aidx,
                                            const float* __restrict__ W4,
                                            const float* __restrict__ W5,
                                            float* __restrict__ Q) {
  __shared__ float tmp[4];
  int b = blockIdx.x, j = threadIdx.x;
  float s = blockSum256(h[(size_t)(NN + b) * DD + j] * W4[j], tmp);
  int a = aidx[b];
  float za = h[(size_t)a * DD + j];
  float q = blockSum256(fmaxf(za * s, 0.f) * W5[j], tmp);
  if (j == 0) Q[b] = q;
}

// ---------------------------------------------------------------- launcher
extern "C" void kernel_launch(void* const* d_in, const int* in_sizes, int n_in,
                              void* d_out, int out_size, void* d_ws, size_t ws_size,
                              hipStream_t stream) {
  (void)in_sizes; (void)n_in; (void)out_size; (void)ws_size;
  const int*   edge_src = (const int*)d_in[0];
  const int*   edge_dst = (const int*)d_in[1];
  const float* edge_w   = (const float*)d_in[2];
  const int*   bassign  = (const int*)d_in[3];
  const int*   aidx     = (const int*)d_in[4];
  const float* Xf       = (const float*)d_in[5];
  const float* Xs       = (const float*)d_in[6];
  const float* W1       = (const float*)d_in[7];
  const float* W2       = (const float*)d_in[8];
  const float* W3       = (const float*)d_in[9];
  const float* linW     = (const float*)d_in[10];
  const float* linB     = (const float*)d_in[11];
  const float* W4       = (const float*)d_in[12];
  const float* W5       = (const float*)d_in[13];
  float* Q = (float*)d_out;

  char* base = (char*)d_ws;
  const size_t NB = (size_t)NT * DD * 4;   // rows include hs
  float* hA   = (float*)(base);
  float* hnv  = (float*)(base + NB);
  float* hB   = (float*)(base + 2 * NB);
  size_t o = 3 * NB;
  short* Bth  = (short*)(base + o); o += (size_t)DD * 512 * 2;
  short* Btl  = (short*)(base + o); o += (size_t)DD * 512 * 2;
  long long* sedge = (long long*)(base + o); o += (size_t)EE * 8;
  int*   snode= (int*)(base + o);   o += (size_t)NN * 4;
  int*   cntn = (int*)(base + o);   o += (size_t)NN * 4;
  int*   cntb = (int*)(base + o);   o += (size_t)BB * 4;   // contiguous with cntn
  int*   offn = (int*)(base + o);   o += (size_t)(NN + 4) * 4;
  int*   offb = (int*)(base + o);   o += (size_t)(BB + 4) * 4;
  int*   curn = (int*)(base + o);   o += (size_t)NN * 4;
  int*   curb = (int*)(base + o);   o += (size_t)BB * 4;

  hipMemsetAsync(cntn, 0, (size_t)(NN + BB) * 4, stream);

  kEncCount<<<NCB + 512 + NT / 4, 256, 0, stream>>>(Xf, Xs, W1, hA,
                                                    edge_dst, bassign, cntn, cntb,
                                                    W2, W3, linW, Bth, Btl);
  kScan<<<1, 1024, 0, stream>>>(cntn, offn, curn, cntb, offb, curb);
  kScatter<<<(EE + 255) / 256, 256, 0, stream>>>(edge_src, edge_dst, edge_w, bassign,
                                                 curn, curb, sedge, snode);
  float* hc = hA;
  float* hn = hB;
  for (int d = 0; d < DEPTH; d++) {
    kAgg<<<8 * (NT / 8), 512, 0, stream>>>(hc, offn, sedge, offb, snode, hnv);
    kUpdM<<<NT / TRU, 256, 0, stream>>>(hc, hnv, Bth, Btl, linB, hn);
    float* sw2 = hc; hc = hn; hn = sw2;
  }
  kDec<<<BB, 256, 0, stream>>>(hc, aidx, W4, W5, Q);
}

// Round 13
// 373.968 us; speedup vs baseline: 2.6248x; 1.0583x over previous
//
#include <hip/hip_runtime.h>

#define NN 20000
#define EE 320000
#define BB 64
#define DD 256
#define DEPTH 3
#define NT (NN + BB)   // h rows + hs rows appended (NT = 20064 = 32*627 = 8*2508)

typedef __attribute__((ext_vector_type(8))) short short8;
typedef __attribute__((ext_vector_type(4))) float floatx4;

// ---------------------------------------------------------------- bf16 split helpers
__device__ __forceinline__ short f2bf(float x) {
  union { float f; unsigned u; } v; v.f = x;
  unsigned r = v.u + 0x7fffu + ((v.u >> 16) & 1u);  // RNE
  return (short)(r >> 16);
}
__device__ __forceinline__ float bf2f(short s) {
  union { unsigned u; float f; } v; v.u = ((unsigned)(unsigned short)s) << 16;
  return v.f;
}

// ---------------------------------------------------------------- reductions
__device__ __forceinline__ float blockSum256(float v, float* tmp) {
  #pragma unroll
  for (int o = 32; o > 0; o >>= 1) v += __shfl_down(v, o, 64);
  if ((threadIdx.x & 63) == 0) tmp[threadIdx.x >> 6] = v;
  __syncthreads();
  float r = tmp[0] + tmp[1] + tmp[2] + tmp[3];
  __syncthreads();
  return r;
}

// ---------------------------------------------------------------- kPre: rank atomics + kM + encode
// SINGLE atomic pass over edges: rank[e] = atomicAdd(curn[dst],1) -- the return value
// is the within-node rank, so kScatter's second 320K-atomic pass is eliminated
// (round-12 evidence: kEncCount 46us @ VALU 8% = random-atomic latency, and kScatter
// repeated the identical pass). Batch ranks via two-level LDS hist (64-bin hot line).
// Blocks: [0,NCB) ranks; [NCB,NCB+512) B-matrix build; rest encode (wave-per-row).
#define NCB ((EE + 255) / 256)   // 1250
__global__ __launch_bounds__(256) void kPre(const float* __restrict__ X,
                                            const float* __restrict__ Xs,
                                            const float* __restrict__ W1,
                                            float* __restrict__ h,
                                            const int* __restrict__ dst,
                                            const int* __restrict__ bassign,
                                            int* curn, int* curb,
                                            int* __restrict__ rank,
                                            int* __restrict__ rankB,
                                            const float* __restrict__ W2,
                                            const float* __restrict__ W3,
                                            const float* __restrict__ linW,
                                            short* __restrict__ Bth,
                                            short* __restrict__ Btl) {
  __shared__ int hb[64], rs[64], hc[64];
  int bid = blockIdx.x, j = threadIdx.x;
  if (bid < NCB) {
    if (j < 64) { hb[j] = 0; hc[j] = 0; }
    __syncthreads();
    int t = bid * 256 + j;
    int b = -1;
    if (t < NN) { b = bassign[t]; atomicAdd(&hb[b], 1); }
    __syncthreads();
    if (j < 64 && hb[j] > 0) rs[j] = atomicAdd(&curb[j], hb[j]);
    __syncthreads();
    if (t < NN) rankB[t] = rs[b] + atomicAdd(&hc[b], 1);
    if (t < EE) rank[t] = atomicAdd(&curn[dst[t]], 1);
  } else if (bid < NCB + 512) {
    // ---- M2 = W2 @ linW[0:256,:], M3 = W3 @ linW[256:512,:], split-transposed
    int i = (bid - NCB) & 255;
    bool second = (bid - NCB) >= 256;
    const float* W = second ? W3 : W2;
    const float* L = linW + (second ? DD * DD : 0);
    float acc = 0.f;
    #pragma unroll 4
    for (int k = 0; k < DD; k++) acc = fmaf(W[i * DD + k], L[k * DD + j], acc);
    short hi = f2bf(acc);
    short lo = f2bf(acc - bf2f(hi));
    int kk = second ? (DD + i) : i;
    Bth[(size_t)j * 512 + kk] = hi;
    Btl[(size_t)j * 512 + kk] = lo;
  } else {
    int r = (bid - NCB - 512) * 4 + (j >> 6);     // wave-per-row
    int lane = j & 63, c0 = lane * 4;
    const float* x = (r < NN) ? (X + (size_t)r * 2) : (Xs + (size_t)(r - NN) * 2);
    float x0 = x[0], x1 = x[1];
    float4 wa = *(const float4*)(W1 + c0);
    float4 wb = *(const float4*)(W1 + DD + c0);
    float4 v;
    v.x = fmaxf(fmaf(x0, wa.x, x1 * wb.x), 0.f);
    v.y = fmaxf(fmaf(x0, wa.y, x1 * wb.y), 0.f);
    v.z = fmaxf(fmaf(x0, wa.z, x1 * wb.z), 0.f);
    v.w = fmaxf(fmaf(x0, wa.w, x1 * wb.w), 0.f);
    float ss = v.x * v.x + v.y * v.y + v.z * v.z + v.w * v.w;
    #pragma unroll
    for (int o = 1; o < 64; o <<= 1) ss += __shfl_xor(ss, o, 64);
    float inv = 1.f / fmaxf(sqrtf(ss), 1e-12f);
    v.x *= inv; v.y *= inv; v.z *= inv; v.w *= inv;
    *(float4*)(h + (size_t)r * DD + c0) = v;
  }
}

// ---------------------------------------------------------------- CSR scan (counts live in curn/curb)
__global__ __launch_bounds__(1024) void kScan(const int* __restrict__ curn,
                                              int* offn,
                                              const int* __restrict__ curb,
                                              int* offb) {
  __shared__ int sums[1024];
  int t = threadIdx.x;
  const int CH = 20;  // 1024*20 = 20480 >= NN
  int base = t * CH;
  int local[CH];
  int s = 0;
  #pragma unroll
  for (int i = 0; i < CH; i++) {
    int idx = base + i;
    int v = (idx < NN) ? curn[idx] : 0;
    local[i] = s;
    s += v;
  }
  sums[t] = s;
  __syncthreads();
  for (int o = 1; o < 1024; o <<= 1) {
    int x = (t >= o) ? sums[t - o] : 0;
    __syncthreads();
    sums[t] += x;
    __syncthreads();
  }
  int excl = sums[t] - s;
  #pragma unroll
  for (int i = 0; i < CH; i++) {
    int idx = base + i;
    if (idx < NN) offn[idx] = excl + local[i];
  }
  if (t == 1023) offn[NN] = sums[1023];
  // batch offsets: 64-lane shuffle scan (first wave)
  if (t < 64) {
    int v = curb[t];
    int incl = v;
    #pragma unroll
    for (int o = 1; o < 64; o <<= 1) {
      int x = __shfl_up(incl, o, 64);
      if (t >= o) incl += x;
    }
    offb[t] = incl - v;
    if (t == 63) offb[BB] = incl;
  }
}

// ---------------------------------------------------------------- kPlace: rank -> position, no atomics
__global__ __launch_bounds__(256) void kPlace(const int* __restrict__ src,
                                              const int* __restrict__ dst,
                                              const float* __restrict__ w,
                                              const int* __restrict__ bassign,
                                              const int* __restrict__ offn,
                                              const int* __restrict__ offb,
                                              const int* __restrict__ rank,
                                              const int* __restrict__ rankB,
                                              long long* sedge, int* snode) {
  int t = blockIdx.x * 256 + threadIdx.x;
  if (t < EE) {
    unsigned long long e = (unsigned long long)(unsigned)src[t]
                         | ((unsigned long long)(unsigned)__float_as_int(w[t]) << 32);
    sedge[offn[dst[t]] + rank[t]] = (long long)e;
  }
  if (t < NN) snode[offb[bassign[t]] + rankB[t]] = t;
}

// ---------------------------------------------------------------- aggregation (XCD-sliced, 8 waves = 8 nodes)
// STRUCTURAL FLOOR (declared): 2.56M distinct 128B gather lines/dispatch = 10K/CU;
// at ~350cyc L2-hit-under-load and ~32 outstanding L1 misses/CU -> 1 line/10.9cyc
// -> 45.5us model vs 46.5 measured (3%). Rounds 7/9/12 structures all converge here.
#define ECAP 1024   // staged edges per chunk (8 KB)
__global__ __launch_bounds__(512) void kAgg(const float* __restrict__ h,
                                            const int* __restrict__ offn,
                                            const long long* __restrict__ sedge,
                                            const int* __restrict__ offb,
                                            const int* __restrict__ snode,
                                            float* __restrict__ hnv) {
  __shared__ __align__(16) long long Led[ECAP];
  int bid = blockIdx.x;
  int slice = bid & 7, group = bid >> 3;      // group 0..2507
  int t = threadIdx.x;
  int w = t >> 6, lane = t & 63;
  int eg = lane >> 3;          // edge group 0..7
  int pc = lane & 7;           // float4 piece 0..7
  int colB = slice * 32 + pc * 4;
  float4 acc = make_float4(0.f, 0.f, 0.f, 0.f);

  if (group < 8) {
    // ---- batch rows: nodes 0..63 (8 per block), snode index list (weight 1)
    int b0 = group * 8;
    int s0 = offb[b0], e0 = offb[b0 + 8];
    int sW = offb[b0 + w], eW = offb[b0 + w + 1];
    int* Li = (int*)Led;
    for (int base = s0; base < e0; base += 2 * ECAP) {
      int cnt = min(e0 - base, 2 * ECAP);
      __syncthreads();
      for (int i = t; i < cnt; i += 512) Li[i] = snode[base + i];
      __syncthreads();
      int lo = max(sW, base), hi = min(eW, base + cnt);
      for (int i = lo; i < hi; i += 16) {
        int i0 = i + eg, i1 = i + 8 + eg;
        int n0 = Li[min(i0, hi - 1) - base];
        int n1 = Li[min(i1, hi - 1) - base];
        float w0 = (i0 < hi) ? 1.f : 0.f;
        float w1 = (i1 < hi) ? 1.f : 0.f;
        float4 v0 = *(const float4*)(h + (size_t)n0 * DD + colB);
        float4 v1 = *(const float4*)(h + (size_t)n1 * DD + colB);
        acc.x = fmaf(w0, v0.x, fmaf(w1, v1.x, acc.x));
        acc.y = fmaf(w0, v0.y, fmaf(w1, v1.y, acc.y));
        acc.z = fmaf(w0, v0.z, fmaf(w1, v1.z, acc.z));
        acc.w = fmaf(w0, v0.w, fmaf(w1, v1.w, acc.w));
      }
    }
    #pragma unroll
    for (int o = 8; o < 64; o <<= 1) {
      acc.x += __shfl_xor(acc.x, o, 64);
      acc.y += __shfl_xor(acc.y, o, 64);
      acc.z += __shfl_xor(acc.z, o, 64);
      acc.w += __shfl_xor(acc.w, o, 64);
    }
    if (eg == 0) *(float4*)(hnv + (size_t)(NN + b0 + w) * DD + colB) = acc;
  } else {
    // ---- edge nodes, 8 per block
    int first = (group - 8) * 8;
    int s0 = offn[first], e0 = offn[first + 8];
    int sW = offn[first + w], eW = offn[first + w + 1];
    for (int base = s0; base < e0; base += ECAP) {
      int cnt = min(e0 - base, ECAP);
      __syncthreads();
      for (int i = t; i < cnt; i += 512) Led[i] = sedge[base + i];
      __syncthreads();
      int lo = max(sW, base), hi = min(eW, base + cnt);
      for (int i = lo; i < hi; i += 16) {
        int i0 = i + eg, i1 = i + 8 + eg;
        long long e0v = Led[min(i0, hi - 1) - base];
        long long e1v = Led[min(i1, hi - 1) - base];
        float w0 = (i0 < hi) ? __int_as_float((int)(e0v >> 32)) : 0.f;
        float w1 = (i1 < hi) ? __int_as_float((int)(e1v >> 32)) : 0.f;
        unsigned r0 = (unsigned)(e0v & 0xffffffffLL);
        unsigned r1 = (unsigned)(e1v & 0xffffffffLL);
        float4 v0 = *(const float4*)(h + (size_t)r0 * DD + colB);
        float4 v1 = *(const float4*)(h + (size_t)r1 * DD + colB);
        acc.x = fmaf(w0, v0.x, fmaf(w1, v1.x, acc.x));
        acc.y = fmaf(w0, v0.y, fmaf(w1, v1.y, acc.y));
        acc.z = fmaf(w0, v0.z, fmaf(w1, v1.z, acc.z));
        acc.w = fmaf(w0, v0.w, fmaf(w1, v1.w, acc.w));
      }
    }
    #pragma unroll
    for (int o = 8; o < 64; o <<= 1) {
      acc.x += __shfl_xor(acc.x, o, 64);
      acc.y += __shfl_xor(acc.y, o, 64);
      acc.z += __shfl_xor(acc.z, o, 64);
      acc.w += __shfl_xor(acc.w, o, 64);
    }
    if (eg == 0) *(float4*)(hnv + (size_t)(first + w) * DD + colB) = acc;
  }
}

// ---------------------------------------------------------------- MFMA dual-GEMM + fused l2norm
// hOut[r,:] = l2norm( relu( sum_k A'[r,k]*B'[k,c] + lb[c] ) ), A' = [h | hnv] (K=512).
// Tile: 32 rows x 256 cols (full width) per block; 4 waves of 32x64; grid = 627 (exact).
#define TRU 32
#define KC 32
__global__ __launch_bounds__(256) void kUpdM(const float* __restrict__ A,
                                             const float* __restrict__ Av,
                                             const short* __restrict__ Bth,
                                             const short* __restrict__ Btl,
                                             const float* __restrict__ lb,
                                             float* __restrict__ out) {
  __shared__ __align__(16) short Ah[TRU][KC];
  __shared__ __align__(16) short Al[TRU][KC];
  __shared__ __align__(16) short Bh[DD][KC];
  __shared__ __align__(16) short Bl[DD][KC];
  __shared__ float ssq[4][TRU];
  const int t = threadIdx.x;
  const int rb = blockIdx.x * TRU;
  const int wid = t >> 6;
  const int lane = t & 63;
  const int wc = wid * 64;         // wave col offset (4 waves cover 256 cols)
  const int m16 = lane & 15;
  const int kg = lane >> 4;        // 0..3

  floatx4 acc[2][4];
  #pragma unroll
  for (int ct = 0; ct < 4; ct++) {
    float b = lb[wc + ct * 16 + m16];
    #pragma unroll
    for (int rt = 0; rt < 2; rt++) acc[rt][ct] = (floatx4){b, b, b, b};
  }

  for (int kc = 0; kc < 512 / KC; ++kc) {
    const int k0 = kc * KC;
    const float* src = (k0 < DD) ? (A + k0) : (Av + (k0 - DD));
    // ---- stage A (fp32 -> hi/lo bf16), 32 rows x 32 k = 256 float4 (1/thread)
    {
      int r = t >> 3;              // 0..31
      int q = t & 7;               // float4 index within row
      float4 v = *(const float4*)(src + (size_t)(rb + r) * DD + q * 4);
      short s0 = f2bf(v.x), s1 = f2bf(v.y), s2 = f2bf(v.z), s3 = f2bf(v.w);
      short l0 = f2bf(v.x - bf2f(s0)), l1 = f2bf(v.y - bf2f(s1));
      short l2 = f2bf(v.z - bf2f(s2)), l3 = f2bf(v.w - bf2f(s3));
      uint2 whi, wlo;
      whi.x = (unsigned short)s0 | ((unsigned)(unsigned short)s1 << 16);
      whi.y = (unsigned short)s2 | ((unsigned)(unsigned short)s3 << 16);
      wlo.x = (unsigned short)l0 | ((unsigned)(unsigned short)l1 << 16);
      wlo.y = (unsigned short)l2 | ((unsigned)(unsigned short)l3 << 16);
      *(uint2*)&Ah[r][q * 4] = whi;
      *(uint2*)&Al[r][q * 4] = wlo;
    }
    // ---- stage B (pre-split bf16, straight copy), 256 n x 32 k per plane
    #pragma unroll
    for (int it = 0; it < 4; ++it) {
      int idx = t + it * 256;      // 0..1023
      int n = idx >> 2;            // 0..255
      int sg = idx & 3;            // 16B segment
      *(uint4*)&Bh[n][sg * 8] = *((const uint4*)(Bth + (size_t)n * 512 + k0) + sg);
      *(uint4*)&Bl[n][sg * 8] = *((const uint4*)(Btl + (size_t)n * 512 + k0) + sg);
    }
    __syncthreads();
    // ---- fragments + MFMA
    short8 af[2], al_[2], bf_[4], bl_[4];
    #pragma unroll
    for (int rt = 0; rt < 2; rt++) {
      af[rt]  = *(const short8*)&Ah[rt * 16 + m16][kg * 8];
      al_[rt] = *(const short8*)&Al[rt * 16 + m16][kg * 8];
    }
    #pragma unroll
    for (int ct = 0; ct < 4; ct++) {
      bf_[ct] = *(const short8*)&Bh[wc + ct * 16 + m16][kg * 8];
      bl_[ct] = *(const short8*)&Bl[wc + ct * 16 + m16][kg * 8];
    }
    #pragma unroll
    for (int rt = 0; rt < 2; rt++)
      #pragma unroll
      for (int ct = 0; ct < 4; ct++) {
        acc[rt][ct] = __builtin_amdgcn_mfma_f32_16x16x32_bf16(af[rt], bf_[ct], acc[rt][ct], 0, 0, 0);
        acc[rt][ct] = __builtin_amdgcn_mfma_f32_16x16x32_bf16(af[rt], bl_[ct], acc[rt][ct], 0, 0, 0);
        acc[rt][ct] = __builtin_amdgcn_mfma_f32_16x16x32_bf16(al_[rt], bf_[ct], acc[rt][ct], 0, 0, 0);
      }
    __syncthreads();
  }
  // ---- epilogue: relu + row l2norm + store (C/D: col=lane&15, row=(lane>>4)*4+reg)
  float p[2][4];
  #pragma unroll
  for (int rt = 0; rt < 2; rt++)
    #pragma unroll
    for (int reg = 0; reg < 4; reg++) {
      float s = 0.f;
      #pragma unroll
      for (int ct = 0; ct < 4; ct++) {
        float x = fmaxf(acc[rt][ct][reg], 0.f);
        s = fmaf(x, x, s);
      }
      p[rt][reg] = s;
    }
  #pragma unroll
  for (int o = 1; o < 16; o <<= 1)
    #pragma unroll
    for (int rt = 0; rt < 2; rt++)
      #pragma unroll
      for (int reg = 0; reg < 4; reg++)
        p[rt][reg] += __shfl_xor(p[rt][reg], o, 64);
  if (m16 == 0) {
    #pragma unroll
    for (int rt = 0; rt < 2; rt++)
      #pragma unroll
      for (int reg = 0; reg < 4; reg++)
        ssq[wid][rt * 16 + kg * 4 + reg] = p[rt][reg];
  }
  __syncthreads();
  #pragma unroll
  for (int rt = 0; rt < 2; rt++) {
    #pragma unroll
    for (int reg = 0; reg < 4; reg++) {
      int row = rt * 16 + kg * 4 + reg;
      float ss = ssq[0][row] + ssq[1][row] + ssq[2][row] + ssq[3][row];
      float inv = 1.f / fmaxf(sqrtf(ss), 1e-12f);
      #pragma unroll
      for (int ct = 0; ct < 4; ct++) {
        int col = wc + ct * 16 + m16;
        out[(size_t)(rb + row) * DD + col] = fmaxf(acc[rt][ct][reg], 0.f) * inv;
      }
    }
  }
}

// ---------------------------------------------------------------- decode
__global__ __launch_bounds__(256) void kDec(const float* __restrict__ h,
                                            const int* __restrict__ aidx,
                                            const float* __restrict__ W4,
                                            const float* __restrict__ W5,
                                            float* __restrict__ Q) {
  __shared__ float tmp[4];
  int b = blockIdx.x, j = threadIdx.x;
  float s = blockSum256(h[(size_t)(NN + b) * DD + j] * W4[j], tmp);
  int a = aidx[b];
  float za = h[(size_t)a * DD + j];
  float q = blockSum256(fmaxf(za * s, 0.f) * W5[j], tmp);
  if (j == 0) Q[b] = q;
}

// ---------------------------------------------------------------- launcher
extern "C" void kernel_launch(void* const* d_in, const int* in_sizes, int n_in,
                              void* d_out, int out_size, void* d_ws, size_t ws_size,
                              hipStream_t stream) {
  (void)in_sizes; (void)n_in; (void)out_size; (void)ws_size;
  const int*   edge_src = (const int*)d_in[0];
  const int*   edge_dst = (const int*)d_in[1];
  const float* edge_w   = (const float*)d_in[2];
  const int*   bassign  = (const int*)d_in[3];
  const int*   aidx     = (const int*)d_in[4];
  const float* Xf       = (const float*)d_in[5];
  const float* Xs       = (const float*)d_in[6];
  const float* W1       = (const float*)d_in[7];
  const float* W2       = (const float*)d_in[8];
  const float* W3       = (const float*)d_in[9];
  const float* linW     = (const float*)d_in[10];
  const float* linB     = (const float*)d_in[11];
  const float* W4       = (const float*)d_in[12];
  const float* W5       = (const float*)d_in[13];
  float* Q = (float*)d_out;

  char* base = (char*)d_ws;
  const size_t NB = (size_t)NT * DD * 4;   // rows include hs
  float* hA   = (float*)(base);
  float* hnv  = (float*)(base + NB);
  float* hB   = (float*)(base + 2 * NB);
  size_t o = 3 * NB;
  short* Bth  = (short*)(base + o); o += (size_t)DD * 512 * 2;
  short* Btl  = (short*)(base + o); o += (size_t)DD * 512 * 2;
  long long* sedge = (long long*)(base + o); o += (size_t)EE * 8;
  int*   snode= (int*)(base + o);   o += (size_t)NN * 4;
  int*   rank = (int*)(base + o);   o += (size_t)EE * 4;
  int*   rankB= (int*)(base + o);   o += (size_t)NN * 4;
  int*   offn = (int*)(base + o);   o += (size_t)(NN + 4) * 4;
  int*   offb = (int*)(base + o);   o += (size_t)(BB + 4) * 4;
  int*   curn = (int*)(base + o);   o += (size_t)NN * 4;
  int*   curb = (int*)(base + o);   o += (size_t)BB * 4;   // contiguous with curn

  hipMemsetAsync(curn, 0, (size_t)(NN + BB) * 4, stream);

  kPre<<<NCB + 512 + NT / 4, 256, 0, stream>>>(Xf, Xs, W1, hA,
                                               edge_dst, bassign, curn, curb,
                                               rank, rankB,
                                               W2, W3, linW, Bth, Btl);
  kScan<<<1, 1024, 0, stream>>>(curn, offn, curb, offb);
  kPlace<<<(EE + 255) / 256, 256, 0, stream>>>(edge_src, edge_dst, edge_w, bassign,
                                               offn, offb, rank, rankB, sedge, snode);
  float* hc = hA;
  float* hn = hB;
  for (int d = 0; d < DEPTH; d++) {
    kAgg<<<8 * (NT / 8), 512, 0, stream>>>(hc, offn, sedge, offb, snode, hnv);
    kUpdM<<<NT / TRU, 256, 0, stream>>>(hc, hnv, Bth, Btl, linB, hn);
    float* sw2 = hc; hc = hn; hn = sw2;
  }
  kDec<<<BB, 256, 0, stream>>>(hc, aidx, W4, W5, Q);
}